// Round 1
// baseline (1574.020 us; speedup 1.0000x reference)
//
#include <hip/hip_runtime.h>

// BigraphLightModel: two LightGCN propagations.
//   h_ii  = lightgcn(emb_ii,  edges_ii,  3 layers)   [N_II, 64]
//   emb_uiu[item block] = h_ii   (item block is contiguous [N_USERS, N_USERS+N_II))
//   h_uiu = lightgcn(emb_uiu, edges_uiu, 3 layers)   [N_UIU, 64]  -> d_out
//
// Round 0: correctness-first atomic-scatter SpMM. One thread per (edge, dim);
// a 64-lane wave covers one edge's full 64-dim row (coalesced gather + scatter).

#define D      64
#define N_II   100000
#define N_UIU  200000
#define E_II   600000
#define E_UIU  1200000
#define N_USERS 100000

__global__ void k_deg(const int* __restrict__ dst, const float* __restrict__ w,
                      float* __restrict__ deg, int E) {
    int e = blockIdx.x * blockDim.x + threadIdx.x;
    if (e < E) atomicAdd(&deg[dst[e]], w[e]);
}

__global__ void k_dis(float* __restrict__ deg, int N) {
    int i = blockIdx.x * blockDim.x + threadIdx.x;
    if (i < N) {
        float d = deg[i];
        deg[i] = (d > 0.f) ? rsqrtf(d) : 0.f;
    }
}

__global__ void k_norm(const int* __restrict__ src, const int* __restrict__ dst,
                       const float* __restrict__ w, const float* __restrict__ dis,
                       float* __restrict__ nrm, int E) {
    int e = blockIdx.x * blockDim.x + threadIdx.x;
    if (e < E) nrm[e] = dis[src[e]] * w[e] * dis[dst[e]];
}

// y[dst[e], d] += nrm[e] * x[src[e], d]; one thread per (edge, dim).
__global__ void k_spmm(const int* __restrict__ src, const int* __restrict__ dst,
                       const float* __restrict__ nrm, const float* __restrict__ x,
                       float* __restrict__ y, int E) {
    int idx = blockIdx.x * blockDim.x + threadIdx.x;
    int e = idx >> 6;
    if (e < E) {
        int d = idx & 63;
        float v = nrm[e] * x[src[e] * D + d];
        atomicAdd(&y[dst[e] * D + d], v);
    }
}

__global__ void k_scale(float4* __restrict__ out, const float4* __restrict__ x,
                        float a, int n4) {
    int i = blockIdx.x * blockDim.x + threadIdx.x;
    if (i < n4) {
        float4 v = x[i];
        out[i] = make_float4(a * v.x, a * v.y, a * v.z, a * v.w);
    }
}

__global__ void k_axpy(float4* __restrict__ out, const float4* __restrict__ x,
                       float a, int n4) {
    int i = blockIdx.x * blockDim.x + threadIdx.x;
    if (i < n4) {
        float4 o = out[i];
        float4 v = x[i];
        o.x += a * v.x; o.y += a * v.y; o.z += a * v.z; o.w += a * v.w;
        out[i] = o;
    }
}

extern "C" void kernel_launch(void* const* d_in, const int* in_sizes, int n_in,
                              void* d_out, int out_size, void* d_ws, size_t ws_size,
                              hipStream_t stream) {
    const float* emb_ii  = (const float*)d_in[0];
    float*       emb_uiu = (float*)d_in[1];        // mutated; harness restores pre-launch
    const float* w_ii    = (const float*)d_in[2];
    const float* w_uiu   = (const float*)d_in[3];
    const int*   src_ii  = (const int*)d_in[4];
    const int*   dst_ii  = src_ii + E_II;
    const int*   src_uiu = (const int*)d_in[5];
    const int*   dst_uiu = src_uiu + E_UIU;
    float*       out     = (float*)d_out;

    // workspace: bufA | bufB | deg | norm  (~108 MB)
    float* bufA = (float*)d_ws;
    float* bufB = bufA + (size_t)N_UIU * D;
    float* deg  = bufB + (size_t)N_UIU * D;
    float* nrm  = deg + N_UIU;

    const int   B = 256;
    const float alpha = 0.25f;   // 1/(L+1), L=3 for both graphs

    // ================= item-item graph =================
    hipMemsetAsync(deg, 0, (size_t)N_II * sizeof(float), stream);
    k_deg <<<(E_II + B - 1) / B, B, 0, stream>>>(dst_ii, w_ii, deg, E_II);
    k_dis <<<(N_II + B - 1) / B, B, 0, stream>>>(deg, N_II);
    k_norm<<<(E_II + B - 1) / B, B, 0, stream>>>(src_ii, dst_ii, w_ii, deg, nrm, E_II);

    // h_ii accumulates directly into emb_uiu's contiguous item block
    float* hii = emb_uiu + (size_t)N_USERS * D;
    const int n4_ii = N_II * D / 4;
    k_scale<<<(n4_ii + B - 1) / B, B, 0, stream>>>(
        (float4*)hii, (const float4*)emb_ii, alpha, n4_ii);

    {
        const float* xc = emb_ii;
        for (int l = 0; l < 3; ++l) {
            float* xn = (l & 1) ? bufB : bufA;
            hipMemsetAsync(xn, 0, (size_t)N_II * D * sizeof(float), stream);
            int nt = E_II * 64;
            k_spmm<<<(nt + B - 1) / B, B, 0, stream>>>(src_ii, dst_ii, nrm, xc, xn, E_II);
            k_axpy<<<(n4_ii + B - 1) / B, B, 0, stream>>>(
                (float4*)hii, (const float4*)xn, alpha, n4_ii);
            xc = xn;
        }
    }

    // ================= user-item graph =================
    hipMemsetAsync(deg, 0, (size_t)N_UIU * sizeof(float), stream);
    k_deg <<<(E_UIU + B - 1) / B, B, 0, stream>>>(dst_uiu, w_uiu, deg, E_UIU);
    k_dis <<<(N_UIU + B - 1) / B, B, 0, stream>>>(deg, N_UIU);
    k_norm<<<(E_UIU + B - 1) / B, B, 0, stream>>>(src_uiu, dst_uiu, w_uiu, deg, nrm, E_UIU);

    const int n4_uiu = N_UIU * D / 4;
    k_scale<<<(n4_uiu + B - 1) / B, B, 0, stream>>>(
        (float4*)out, (const float4*)emb_uiu, alpha, n4_uiu);

    {
        const float* xc = emb_uiu;
        for (int l = 0; l < 3; ++l) {
            float* xn = (l & 1) ? bufB : bufA;
            hipMemsetAsync(xn, 0, (size_t)N_UIU * D * sizeof(float), stream);
            int nt = E_UIU * 64;
            k_spmm<<<(nt + B - 1) / B, B, 0, stream>>>(src_uiu, dst_uiu, nrm, xc, xn, E_UIU);
            k_axpy<<<(n4_uiu + B - 1) / B, B, 0, stream>>>(
                (float4*)out, (const float4*)xn, alpha, n4_uiu);
            xc = xn;
        }
    }
}

// Round 2
// 1044.211 us; speedup vs baseline: 1.5074x; 1.5074x over previous
//
#include <hip/hip_runtime.h>

// BigraphLightModel — R1: CSR pull-SpMM, no atomics in the hot loop.
//   Per graph: build CSR by dst on device (count -> 3-kernel scan -> scatter),
//   then 3 layers of pull-SpMM (one wave per row, lanes = 64 dims), with the
//   LightGCN mean (alpha * sum of layer outputs) fused into the epilogue.

#define D       64
#define N_II    100000
#define N_UIU   200000
#define E_II    600000
#define E_UIU   1200000
#define N_USERS 100000

// ---------- CSR build ----------

// per-edge: int count + weighted degree (both atomics, build-time only)
__global__ void k_cnt_deg(const int* __restrict__ dst, const float* __restrict__ w,
                          int* __restrict__ cnt, float* __restrict__ deg, int E) {
    int e = blockIdx.x * blockDim.x + threadIdx.x;
    if (e < E) {
        int t = dst[e];
        atomicAdd(&cnt[t], 1);
        atomicAdd(&deg[t], w[e]);
    }
}

__global__ void k_dis(float* __restrict__ deg, int N) {
    int i = blockIdx.x * blockDim.x + threadIdx.x;
    if (i < N) {
        float d = deg[i];
        deg[i] = (d > 0.f) ? rsqrtf(d) : 0.f;   // deg -> deg^{-1/2} in place
    }
}

// per-256-block sums of cnt
__global__ void k_blkred(const int* __restrict__ cnt, int* __restrict__ blk, int N) {
    __shared__ int sh[256];
    int i = blockIdx.x * 256 + threadIdx.x;
    sh[threadIdx.x] = (i < N) ? cnt[i] : 0;
    __syncthreads();
    for (int s = 128; s > 0; s >>= 1) {
        if (threadIdx.x < s) sh[threadIdx.x] += sh[threadIdx.x + s];
        __syncthreads();
    }
    if (threadIdx.x == 0) blk[blockIdx.x] = sh[0];
}

// single-block exclusive scan of block sums (nb <= 1024)
__global__ void k_blkscan(int* __restrict__ blk, int nb) {
    __shared__ int sh[1024];
    int t = threadIdx.x;
    sh[t] = (t < nb) ? blk[t] : 0;
    __syncthreads();
    for (int off = 1; off < 1024; off <<= 1) {
        int v = (t >= off) ? sh[t - off] : 0;
        __syncthreads();
        sh[t] += v;
        __syncthreads();
    }
    if (t < nb) blk[t] = (t > 0) ? sh[t - 1] : 0;  // exclusive
}

// per-block scan of cnt + block offset -> row offsets; cursor starts at roff
__global__ void k_rowoff(const int* __restrict__ cnt, const int* __restrict__ blk,
                         int* __restrict__ roff, int* __restrict__ cursor, int N) {
    __shared__ int sh[256];
    int t = threadIdx.x;
    int i = blockIdx.x * 256 + t;
    int v = (i < N) ? cnt[i] : 0;
    sh[t] = v;
    __syncthreads();
    for (int off = 1; off < 256; off <<= 1) {
        int u = (t >= off) ? sh[t - off] : 0;
        __syncthreads();
        sh[t] += u;
        __syncthreads();
    }
    if (i < N) {
        int o = blk[blockIdx.x] + sh[t] - v;   // exclusive prefix
        roff[i]   = o;
        cursor[i] = o;
    }
}

// scatter edges into CSR slots; fuse gcn_norm value computation
__global__ void k_scatter(const int* __restrict__ src, const int* __restrict__ dst,
                          const float* __restrict__ w, const float* __restrict__ dis,
                          int* __restrict__ cursor, int* __restrict__ csrc,
                          float* __restrict__ cval, int E) {
    int e = blockIdx.x * blockDim.x + threadIdx.x;
    if (e < E) {
        int s = src[e], t = dst[e];
        int pos = atomicAdd(&cursor[t], 1);
        csrc[pos] = s;
        cval[pos] = dis[s] * w[e] * dis[t];
    }
}

// ---------- pull SpMM, fused LightGCN epilogue ----------
// One 64-lane wave per row; lane = dim. acc = sum_j val_j * x[src_j, d].
// if write_x: xn[row] = acc.   out[row] = (init ? alpha*x0[row] : out[row]) + alpha*acc.
__global__ void k_spmm_csr(const int* __restrict__ roff, const int* __restrict__ rend,
                           const int* __restrict__ csrc, const float* __restrict__ cval,
                           const float* __restrict__ x, const float* __restrict__ x0,
                           float* __restrict__ xn, float* __restrict__ out,
                           float alpha, int N, int init, int write_x) {
    int row = blockIdx.x * (blockDim.x >> 6) + (threadIdx.x >> 6);
    if (row >= N) return;
    int d = threadIdx.x & 63;
    int s = roff[row], e = rend[row];
    float acc = 0.f;
    for (int j = s; j < e; ++j) {
        int   sr = csrc[j];       // wave-uniform
        float v  = cval[j];       // wave-uniform
        acc += v * x[sr * D + d]; // coalesced 256B gather
    }
    int o = row * D + d;
    if (write_x) xn[o] = acc;
    float base = init ? (alpha * x0[o]) : out[o];
    out[o] = base + alpha * acc;
}

// ---------- host-side orchestration ----------

static void run_graph(const int* src, const int* dst, const float* w, int E, int N,
                      const float* x0, float* out, float* bufA, float* bufB,
                      int* roff, int* cursor, int* csrc, float* cval,
                      hipStream_t stream) {
    const int B = 256;
    const int nbN = (N + 255) / 256;
    const float alpha = 0.25f;   // 1/(L+1), L=3

    // scratch aliased into bufB (untouched until layer-2 SpMM)
    int*   cnt = (int*)bufB;
    float* deg = (float*)bufB + N;
    int*   blk = (int*)bufB + 2 * N;

    hipMemsetAsync(cnt, 0, (size_t)2 * N * sizeof(int), stream);  // cnt + deg
    k_cnt_deg<<<(E + B - 1) / B, B, 0, stream>>>(dst, w, cnt, deg, E);
    k_dis    <<<nbN, B, 0, stream>>>(deg, N);
    k_blkred <<<nbN, B, 0, stream>>>(cnt, blk, N);
    k_blkscan<<<1, 1024, 0, stream>>>(blk, nbN);
    k_rowoff <<<nbN, B, 0, stream>>>(cnt, blk, roff, cursor, N);
    k_scatter<<<(E + B - 1) / B, B, 0, stream>>>(src, dst, w, deg, cursor, csrc, cval, E);
    // after scatter, cursor[i] == row end

    const int rows_per_blk = B / D;                       // 4
    const int ng = (N + rows_per_blk - 1) / rows_per_blk;
    // layer 0: x0 -> bufA
    k_spmm_csr<<<ng, B, 0, stream>>>(roff, cursor, csrc, cval, x0, x0, bufA, out,
                                     alpha, N, 1, 1);
    // layer 1: bufA -> bufB
    k_spmm_csr<<<ng, B, 0, stream>>>(roff, cursor, csrc, cval, bufA, x0, bufB, out,
                                     alpha, N, 0, 1);
    // layer 2: bufB -> (no x write)
    k_spmm_csr<<<ng, B, 0, stream>>>(roff, cursor, csrc, cval, bufB, x0, nullptr, out,
                                     alpha, N, 0, 0);
}

extern "C" void kernel_launch(void* const* d_in, const int* in_sizes, int n_in,
                              void* d_out, int out_size, void* d_ws, size_t ws_size,
                              hipStream_t stream) {
    const float* emb_ii  = (const float*)d_in[0];
    float*       emb_uiu = (float*)d_in[1];        // mutated; harness restores pre-launch
    const float* w_ii    = (const float*)d_in[2];
    const float* w_uiu   = (const float*)d_in[3];
    const int*   src_ii  = (const int*)d_in[4];
    const int*   dst_ii  = src_ii + E_II;
    const int*   src_uiu = (const int*)d_in[5];
    const int*   dst_uiu = src_uiu + E_UIU;
    float*       out     = (float*)d_out;

    // workspace layout (~113.6 MB):
    //   bufA [N_UIU*D f32] | bufB [N_UIU*D f32] | roff [N_UIU+1] | cursor [N_UIU]
    //   | csrc [E_UIU] | cval [E_UIU]
    float* bufA   = (float*)d_ws;
    float* bufB   = bufA + (size_t)N_UIU * D;
    int*   roff   = (int*)(bufB + (size_t)N_UIU * D);
    int*   cursor = roff + (N_UIU + 1);
    int*   csrc   = cursor + N_UIU;
    float* cval   = (float*)(csrc + E_UIU);

    // ---- item-item graph: h_ii written straight into emb_uiu's item block ----
    float* hii = emb_uiu + (size_t)N_USERS * D;
    run_graph(src_ii, dst_ii, w_ii, E_II, N_II, emb_ii, hii,
              bufA, bufB, roff, cursor, csrc, cval, stream);

    // ---- user-item graph: x0 = emb_uiu (item block now holds h_ii) ----
    run_graph(src_uiu, dst_uiu, w_uiu, E_UIU, N_UIU, emb_uiu, out,
              bufA, bufB, roff, cursor, csrc, cval, stream);
}

// Round 3
// 697.995 us; speedup vs baseline: 2.2551x; 1.4960x over previous
//
#include <hip/hip_runtime.h>

// BigraphLightModel — R2: CSR pull-SpMM with 16-lane row-groups + float4 gathers.
//   R1 was latency-bound (1.9 TB/s, VALU 14%): one serial gather stream per wave.
//   Now each wave handles 4 rows (16 lanes x float4 = 64 dims per row), giving
//   4 independent gather streams per wave + unroll-2 per stream = 8x the MLP.

#define D       64
#define N_II    100000
#define N_UIU   200000
#define E_II    600000
#define E_UIU   1200000
#define N_USERS 100000

// ---------- CSR build ----------

__global__ void k_cnt_deg(const int* __restrict__ dst, const float* __restrict__ w,
                          int* __restrict__ cnt, float* __restrict__ deg, int E) {
    int e = blockIdx.x * blockDim.x + threadIdx.x;
    if (e < E) {
        int t = dst[e];
        atomicAdd(&cnt[t], 1);
        atomicAdd(&deg[t], w[e]);
    }
}

__global__ void k_dis(float* __restrict__ deg, int N) {
    int i = blockIdx.x * blockDim.x + threadIdx.x;
    if (i < N) {
        float d = deg[i];
        deg[i] = (d > 0.f) ? rsqrtf(d) : 0.f;   // deg -> deg^{-1/2} in place
    }
}

__global__ void k_blkred(const int* __restrict__ cnt, int* __restrict__ blk, int N) {
    __shared__ int sh[256];
    int i = blockIdx.x * 256 + threadIdx.x;
    sh[threadIdx.x] = (i < N) ? cnt[i] : 0;
    __syncthreads();
    for (int s = 128; s > 0; s >>= 1) {
        if (threadIdx.x < s) sh[threadIdx.x] += sh[threadIdx.x + s];
        __syncthreads();
    }
    if (threadIdx.x == 0) blk[blockIdx.x] = sh[0];
}

__global__ void k_blkscan(int* __restrict__ blk, int nb) {
    __shared__ int sh[1024];
    int t = threadIdx.x;
    sh[t] = (t < nb) ? blk[t] : 0;
    __syncthreads();
    for (int off = 1; off < 1024; off <<= 1) {
        int v = (t >= off) ? sh[t - off] : 0;
        __syncthreads();
        sh[t] += v;
        __syncthreads();
    }
    if (t < nb) blk[t] = (t > 0) ? sh[t - 1] : 0;  // exclusive
}

__global__ void k_rowoff(const int* __restrict__ cnt, const int* __restrict__ blk,
                         int* __restrict__ roff, int* __restrict__ cursor, int N) {
    __shared__ int sh[256];
    int t = threadIdx.x;
    int i = blockIdx.x * 256 + t;
    int v = (i < N) ? cnt[i] : 0;
    sh[t] = v;
    __syncthreads();
    for (int off = 1; off < 256; off <<= 1) {
        int u = (t >= off) ? sh[t - off] : 0;
        __syncthreads();
        sh[t] += u;
        __syncthreads();
    }
    if (i < N) {
        int o = blk[blockIdx.x] + sh[t] - v;   // exclusive prefix
        roff[i]   = o;
        cursor[i] = o;
    }
}

__global__ void k_scatter(const int* __restrict__ src, const int* __restrict__ dst,
                          const float* __restrict__ w, const float* __restrict__ dis,
                          int* __restrict__ cursor, int* __restrict__ csrc,
                          float* __restrict__ cval, int E) {
    int e = blockIdx.x * blockDim.x + threadIdx.x;
    if (e < E) {
        int s = src[e], t = dst[e];
        int pos = atomicAdd(&cursor[t], 1);
        csrc[pos] = s;
        cval[pos] = dis[s] * w[e] * dis[t];
    }
}

// ---------- pull SpMM: 16-lane group per row, float4 per lane ----------
// group g-lane handles dims [4*(tid&15), +4). 4 rows per wave -> 4 gather streams.
__global__ void k_spmm_csr(const int* __restrict__ roff, const int* __restrict__ rend,
                           const int* __restrict__ csrc, const float* __restrict__ cval,
                           const float4* __restrict__ x, const float4* __restrict__ x0,
                           float4* __restrict__ xn, float4* __restrict__ out,
                           float alpha, int N, int init, int write_x) {
    int row = (blockIdx.x * blockDim.x + threadIdx.x) >> 4;
    if (row >= N) return;
    int g = threadIdx.x & 15;
    int s = rend ? roff[row] : 0;        // (rend always non-null; keeps codegen simple)
    int e = rend[row];
    float4 acc = make_float4(0.f, 0.f, 0.f, 0.f);
    int j = s;
    for (; j + 1 < e; j += 2) {          // unroll-2: two gathers in flight
        int   s0 = csrc[j],   s1 = csrc[j + 1];
        float v0 = cval[j],   v1 = cval[j + 1];
        float4 a0 = x[s0 * 16 + g];
        float4 a1 = x[s1 * 16 + g];
        acc.x += v0 * a0.x + v1 * a1.x;
        acc.y += v0 * a0.y + v1 * a1.y;
        acc.z += v0 * a0.z + v1 * a1.z;
        acc.w += v0 * a0.w + v1 * a1.w;
    }
    if (j < e) {
        int   s0 = csrc[j];
        float v0 = cval[j];
        float4 a0 = x[s0 * 16 + g];
        acc.x += v0 * a0.x; acc.y += v0 * a0.y;
        acc.z += v0 * a0.z; acc.w += v0 * a0.w;
    }
    int o = row * 16 + g;
    if (write_x) xn[o] = acc;
    float4 base;
    if (init) {
        float4 t = x0[o];
        base = make_float4(alpha * t.x, alpha * t.y, alpha * t.z, alpha * t.w);
    } else {
        base = out[o];
    }
    out[o] = make_float4(base.x + alpha * acc.x, base.y + alpha * acc.y,
                         base.z + alpha * acc.z, base.w + alpha * acc.w);
}

// ---------- host-side orchestration ----------

static void run_graph(const int* src, const int* dst, const float* w, int E, int N,
                      const float* x0, float* out, float* bufA, float* bufB,
                      int* roff, int* cursor, int* csrc, float* cval,
                      hipStream_t stream) {
    const int B = 256;
    const int nbN = (N + 255) / 256;
    const float alpha = 0.25f;   // 1/(L+1), L=3

    // scratch aliased into bufB (untouched until layer-1 SpMM writes it)
    int*   cnt = (int*)bufB;
    float* deg = (float*)bufB + N;
    int*   blk = (int*)bufB + 2 * N;

    hipMemsetAsync(cnt, 0, (size_t)2 * N * sizeof(int), stream);  // cnt + deg
    k_cnt_deg<<<(E + B - 1) / B, B, 0, stream>>>(dst, w, cnt, deg, E);
    k_dis    <<<nbN, B, 0, stream>>>(deg, N);
    k_blkred <<<nbN, B, 0, stream>>>(cnt, blk, N);
    k_blkscan<<<1, 1024, 0, stream>>>(blk, nbN);
    k_rowoff <<<nbN, B, 0, stream>>>(cnt, blk, roff, cursor, N);
    k_scatter<<<(E + B - 1) / B, B, 0, stream>>>(src, dst, w, deg, cursor, csrc, cval, E);
    // after scatter, cursor[i] == row end

    const int rows_per_blk = B / 16;                      // 16 rows per 256-thr block
    const int ng = (N + rows_per_blk - 1) / rows_per_blk;
    // layer 0: x0 -> bufA
    k_spmm_csr<<<ng, B, 0, stream>>>(roff, cursor, csrc, cval,
                                     (const float4*)x0, (const float4*)x0,
                                     (float4*)bufA, (float4*)out, alpha, N, 1, 1);
    // layer 1: bufA -> bufB
    k_spmm_csr<<<ng, B, 0, stream>>>(roff, cursor, csrc, cval,
                                     (const float4*)bufA, (const float4*)x0,
                                     (float4*)bufB, (float4*)out, alpha, N, 0, 1);
    // layer 2: bufB -> (no x write)
    k_spmm_csr<<<ng, B, 0, stream>>>(roff, cursor, csrc, cval,
                                     (const float4*)bufB, (const float4*)x0,
                                     nullptr, (float4*)out, alpha, N, 0, 0);
}

extern "C" void kernel_launch(void* const* d_in, const int* in_sizes, int n_in,
                              void* d_out, int out_size, void* d_ws, size_t ws_size,
                              hipStream_t stream) {
    const float* emb_ii  = (const float*)d_in[0];
    float*       emb_uiu = (float*)d_in[1];        // mutated; harness restores pre-launch
    const float* w_ii    = (const float*)d_in[2];
    const float* w_uiu   = (const float*)d_in[3];
    const int*   src_ii  = (const int*)d_in[4];
    const int*   dst_ii  = src_ii + E_II;
    const int*   src_uiu = (const int*)d_in[5];
    const int*   dst_uiu = src_uiu + E_UIU;
    float*       out     = (float*)d_out;

    // workspace layout (~113.6 MB):
    //   bufA [N_UIU*D f32] | bufB [N_UIU*D f32] | roff [N_UIU+1] | cursor [N_UIU]
    //   | csrc [E_UIU] | cval [E_UIU]
    float* bufA   = (float*)d_ws;
    float* bufB   = bufA + (size_t)N_UIU * D;
    int*   roff   = (int*)(bufB + (size_t)N_UIU * D);
    int*   cursor = roff + (N_UIU + 1);
    int*   csrc   = cursor + N_UIU;
    float* cval   = (float*)(csrc + E_UIU);

    // ---- item-item graph: h_ii written straight into emb_uiu's item block ----
    float* hii = emb_uiu + (size_t)N_USERS * D;
    run_graph(src_ii, dst_ii, w_ii, E_II, N_II, emb_ii, hii,
              bufA, bufB, roff, cursor, csrc, cval, stream);

    // ---- user-item graph: x0 = emb_uiu (item block now holds h_ii) ----
    run_graph(src_uiu, dst_uiu, w_uiu, E_UIU, N_UIU, emb_uiu, out,
              bufA, bufB, roff, cursor, csrc, cval, stream);
}

// Round 4
// 636.385 us; speedup vs baseline: 2.4734x; 1.0968x over previous
//
#include <hip/hip_runtime.h>

// BigraphLightModel — R3: linked-list CSR build, 1 atomic per edge (was 3).
//   R2 profile: k_cnt_deg (2 scattered atomics/edge) = 107us uiu at 0.3% VALU —
//   scattered-atomic-throughput bound (~22G/s). Replace count+scan+scatter
//   (3 atomics/edge) with atomicExch bucketing (1/edge) + two atomic-free
//   node-parallel chain walks. SpMM (R2's 16-lane float4 pull) unchanged.

#define D       64
#define N_II    100000
#define N_UIU   200000
#define E_II    600000
#define E_UIU   1200000
#define N_USERS 100000
#define HPAD    16        // head[] stride in ints (64B) — one line per node

// ---------- CSR build (linked-list bucketing) ----------

// nxt[e] = old head[dst[e]]; head[dst[e]] = e.  Only atomic pass.
__global__ void k_exch(const int* __restrict__ dst, int* __restrict__ head,
                       int* __restrict__ nxt, int E) {
    int e = blockIdx.x * blockDim.x + threadIdx.x;
    if (e < E) nxt[e] = atomicExch(&head[dst[e] * HPAD], e);
}

// walk chain: cnt[i] = in-degree, dis[i] = rsqrt(weighted deg) (0 if empty)
__global__ void k_walk(const int* __restrict__ head, const int* __restrict__ nxt,
                       const float* __restrict__ w, int* __restrict__ cnt,
                       float* __restrict__ dis, int N) {
    int i = blockIdx.x * blockDim.x + threadIdx.x;
    if (i >= N) return;
    int e = head[i * HPAD];
    int c = 0;
    float dg = 0.f;
    while (e >= 0) {
        dg += w[e];
        c++;
        e = nxt[e];
    }
    cnt[i] = c;
    dis[i] = (dg > 0.f) ? rsqrtf(dg) : 0.f;
}

__global__ void k_blkred(const int* __restrict__ cnt, int* __restrict__ blk, int N) {
    __shared__ int sh[256];
    int i = blockIdx.x * 256 + threadIdx.x;
    sh[threadIdx.x] = (i < N) ? cnt[i] : 0;
    __syncthreads();
    for (int s = 128; s > 0; s >>= 1) {
        if (threadIdx.x < s) sh[threadIdx.x] += sh[threadIdx.x + s];
        __syncthreads();
    }
    if (threadIdx.x == 0) blk[blockIdx.x] = sh[0];
}

__global__ void k_blkscan(int* __restrict__ blk, int nb) {
    __shared__ int sh[1024];
    int t = threadIdx.x;
    sh[t] = (t < nb) ? blk[t] : 0;
    __syncthreads();
    for (int off = 1; off < 1024; off <<= 1) {
        int v = (t >= off) ? sh[t - off] : 0;
        __syncthreads();
        sh[t] += v;
        __syncthreads();
    }
    if (t < nb) blk[t] = (t > 0) ? sh[t - 1] : 0;  // exclusive
}

__global__ void k_rowoff(const int* __restrict__ cnt, const int* __restrict__ blk,
                         int* __restrict__ roff, int* __restrict__ rend, int N) {
    __shared__ int sh[256];
    int t = threadIdx.x;
    int i = blockIdx.x * 256 + t;
    int v = (i < N) ? cnt[i] : 0;
    sh[t] = v;
    __syncthreads();
    for (int off = 1; off < 256; off <<= 1) {
        int u = (t >= off) ? sh[t - off] : 0;
        __syncthreads();
        sh[t] += u;
        __syncthreads();
    }
    if (i < N) {
        int o = blk[blockIdx.x] + sh[t] - v;   // exclusive prefix
        roff[i] = o;
        rend[i] = o + v;
    }
}

// walk chain again, fill csrc/cval (fused gcn_norm). Atomic-free.
__global__ void k_fill(const int* __restrict__ head, const int* __restrict__ nxt,
                       const int* __restrict__ src, const float* __restrict__ w,
                       const float* __restrict__ dis, const int* __restrict__ roff,
                       int* __restrict__ csrc, float* __restrict__ cval, int N) {
    int i = blockIdx.x * blockDim.x + threadIdx.x;
    if (i >= N) return;
    float di = dis[i];
    int pos = roff[i];
    int e = head[i * HPAD];
    while (e >= 0) {
        int s = src[e];
        csrc[pos] = s;
        cval[pos] = di * w[e] * dis[s];
        pos++;
        e = nxt[e];
    }
}

// ---------- pull SpMM: 16-lane group per row, float4 per lane (R2) ----------
__global__ void k_spmm_csr(const int* __restrict__ roff, const int* __restrict__ rend,
                           const int* __restrict__ csrc, const float* __restrict__ cval,
                           const float4* __restrict__ x, const float4* __restrict__ x0,
                           float4* __restrict__ xn, float4* __restrict__ out,
                           float alpha, int N, int init, int write_x) {
    int row = (blockIdx.x * blockDim.x + threadIdx.x) >> 4;
    if (row >= N) return;
    int g = threadIdx.x & 15;
    int s = roff[row];
    int e = rend[row];
    float4 acc = make_float4(0.f, 0.f, 0.f, 0.f);
    int j = s;
    for (; j + 1 < e; j += 2) {          // unroll-2: two gathers in flight
        int   s0 = csrc[j],   s1 = csrc[j + 1];
        float v0 = cval[j],   v1 = cval[j + 1];
        float4 a0 = x[s0 * 16 + g];
        float4 a1 = x[s1 * 16 + g];
        acc.x += v0 * a0.x + v1 * a1.x;
        acc.y += v0 * a0.y + v1 * a1.y;
        acc.z += v0 * a0.z + v1 * a1.z;
        acc.w += v0 * a0.w + v1 * a1.w;
    }
    if (j < e) {
        int   s0 = csrc[j];
        float v0 = cval[j];
        float4 a0 = x[s0 * 16 + g];
        acc.x += v0 * a0.x; acc.y += v0 * a0.y;
        acc.z += v0 * a0.z; acc.w += v0 * a0.w;
    }
    int o = row * 16 + g;
    if (write_x) xn[o] = acc;
    float4 base;
    if (init) {
        float4 t = x0[o];
        base = make_float4(alpha * t.x, alpha * t.y, alpha * t.z, alpha * t.w);
    } else {
        base = out[o];
    }
    out[o] = make_float4(base.x + alpha * acc.x, base.y + alpha * acc.y,
                         base.z + alpha * acc.z, base.w + alpha * acc.w);
}

// ---------- host-side orchestration ----------

static void run_graph(const int* src, const int* dst, const float* w, int E, int N,
                      const float* x0, float* out, float* bufA, float* bufB,
                      int* roff, int* rend, int* csrc, float* cval,
                      hipStream_t stream) {
    const int B = 256;
    const int nbE = (E + B - 1) / B;
    const int nbN = (N + B - 1) / B;
    const float alpha = 0.25f;   // 1/(L+1), L=3

    // build scratch aliased into bufB (free until SpMM layer 1 writes it):
    //   cnt [N] | dis [N] | blk [1024] | head [N*HPAD] | nxt [E]
    int*   cnt  = (int*)bufB;
    float* dis  = (float*)bufB + N;
    int*   blk  = (int*)bufB + 2 * N;
    int*   head = (int*)bufB + 2 * N + 1024;
    int*   nxt  = head + (size_t)N * HPAD;

    hipMemsetAsync(head, 0xFF, (size_t)N * HPAD * sizeof(int), stream);  // head = -1
    k_exch   <<<nbE, B, 0, stream>>>(dst, head, nxt, E);
    k_walk   <<<nbN, B, 0, stream>>>(head, nxt, w, cnt, dis, N);
    k_blkred <<<nbN, B, 0, stream>>>(cnt, blk, N);
    k_blkscan<<<1, 1024, 0, stream>>>(blk, nbN);
    k_rowoff <<<nbN, B, 0, stream>>>(cnt, blk, roff, rend, N);
    k_fill   <<<nbN, B, 0, stream>>>(head, nxt, src, w, dis, roff, csrc, cval, N);

    const int rows_per_blk = B / 16;                      // 16 rows per 256-thr block
    const int ng = (N + rows_per_blk - 1) / rows_per_blk;
    // layer 0: x0 -> bufA
    k_spmm_csr<<<ng, B, 0, stream>>>(roff, rend, csrc, cval,
                                     (const float4*)x0, (const float4*)x0,
                                     (float4*)bufA, (float4*)out, alpha, N, 1, 1);
    // layer 1: bufA -> bufB
    k_spmm_csr<<<ng, B, 0, stream>>>(roff, rend, csrc, cval,
                                     (const float4*)bufA, (const float4*)x0,
                                     (float4*)bufB, (float4*)out, alpha, N, 0, 1);
    // layer 2: bufB -> (no x write)
    k_spmm_csr<<<ng, B, 0, stream>>>(roff, rend, csrc, cval,
                                     (const float4*)bufB, (const float4*)x0,
                                     nullptr, (float4*)out, alpha, N, 0, 0);
}

extern "C" void kernel_launch(void* const* d_in, const int* in_sizes, int n_in,
                              void* d_out, int out_size, void* d_ws, size_t ws_size,
                              hipStream_t stream) {
    const float* emb_ii  = (const float*)d_in[0];
    float*       emb_uiu = (float*)d_in[1];        // mutated; harness restores pre-launch
    const float* w_ii    = (const float*)d_in[2];
    const float* w_uiu   = (const float*)d_in[3];
    const int*   src_ii  = (const int*)d_in[4];
    const int*   dst_ii  = src_ii + E_II;
    const int*   src_uiu = (const int*)d_in[5];
    const int*   dst_uiu = src_uiu + E_UIU;
    float*       out     = (float*)d_out;

    // workspace layout (~113.6 MB):
    //   bufA [N_UIU*D f32] | bufB [N_UIU*D f32] | roff [N_UIU] | rend [N_UIU]
    //   | csrc [E_UIU] | cval [E_UIU]
    // (build scratch — cnt/dis/blk/head/nxt — aliased inside bufB; ~19.2 MB < 51.2 MB)
    float* bufA = (float*)d_ws;
    float* bufB = bufA + (size_t)N_UIU * D;
    int*   roff = (int*)(bufB + (size_t)N_UIU * D);
    int*   rend = roff + N_UIU;
    int*   csrc = rend + N_UIU;
    float* cval = (float*)(csrc + E_UIU);

    // ---- item-item graph: h_ii written straight into emb_uiu's item block ----
    float* hii = emb_uiu + (size_t)N_USERS * D;
    run_graph(src_ii, dst_ii, w_ii, E_II, N_II, emb_ii, hii,
              bufA, bufB, roff, rend, csrc, cval, stream);

    // ---- user-item graph: x0 = emb_uiu (item block now holds h_ii) ----
    run_graph(src_uiu, dst_uiu, w_uiu, E_UIU, N_UIU, emb_uiu, out,
              bufA, bufB, roff, rend, csrc, cval, stream);
}

// Round 5
// 504.623 us; speedup vs baseline: 3.1192x; 1.2611x over previous
//
#include <hip/hip_runtime.h>

// BigraphLightModel — R4: rank-based CSR build (no pointer chase) + bf16 SpMM.
//   R3 profile: k_fill 77us at FETCH=184MB — chain-order scattered reads of
//   nxt/src/w. Replace with atomicAdd-rank (1 scattered atomic/edge, coalesced
//   everything else). SpMM: bf16 gather operand (halves gather+xn bytes),
//   8-lane row-groups (8 rows/wave), out-accumulation fused into final layer
//   only: out = alpha*(x0 + x1 + x2 + A*x2).

#define D       64
#define N_II    100000
#define N_UIU   200000
#define E_II    600000
#define E_UIU   1200000
#define N_USERS 100000

// ---------- bf16 helpers ----------
__device__ __forceinline__ unsigned short f2bf(float f) {
    unsigned u = __float_as_uint(f);
    u += 0x7fffu + ((u >> 16) & 1u);          // round-to-nearest-even
    return (unsigned short)(u >> 16);
}
__device__ __forceinline__ void bf8_fma(float acc[8], uint4 p, float v) {
    acc[0] += v * __uint_as_float(p.x << 16);
    acc[1] += v * __uint_as_float(p.x & 0xffff0000u);
    acc[2] += v * __uint_as_float(p.y << 16);
    acc[3] += v * __uint_as_float(p.y & 0xffff0000u);
    acc[4] += v * __uint_as_float(p.z << 16);
    acc[5] += v * __uint_as_float(p.z & 0xffff0000u);
    acc[6] += v * __uint_as_float(p.w << 16);
    acc[7] += v * __uint_as_float(p.w & 0xffff0000u);
}
__device__ __forceinline__ void bf8_add(float acc[8], uint4 p) {
    acc[0] += __uint_as_float(p.x << 16);
    acc[1] += __uint_as_float(p.x & 0xffff0000u);
    acc[2] += __uint_as_float(p.y << 16);
    acc[3] += __uint_as_float(p.y & 0xffff0000u);
    acc[4] += __uint_as_float(p.z << 16);
    acc[5] += __uint_as_float(p.z & 0xffff0000u);
    acc[6] += __uint_as_float(p.w << 16);
    acc[7] += __uint_as_float(p.w & 0xffff0000u);
}
__device__ __forceinline__ uint4 pack8(const float a[8]) {
    uint4 r;
    r.x = (unsigned)f2bf(a[0]) | ((unsigned)f2bf(a[1]) << 16);
    r.y = (unsigned)f2bf(a[2]) | ((unsigned)f2bf(a[3]) << 16);
    r.z = (unsigned)f2bf(a[4]) | ((unsigned)f2bf(a[5]) << 16);
    r.w = (unsigned)f2bf(a[6]) | ((unsigned)f2bf(a[7]) << 16);
    return r;
}

// ---------- CSR build ----------

// rank[e] = arrival order of e within its dst bucket; cnt[i] ends as in-degree.
__global__ void k_cnt_rank(const int* __restrict__ dst, int* __restrict__ cnt,
                           int* __restrict__ rank, int E) {
    int e = blockIdx.x * blockDim.x + threadIdx.x;
    if (e < E) rank[e] = atomicAdd(&cnt[dst[e]], 1);
}

__global__ void k_blkred(const int* __restrict__ cnt, int* __restrict__ blk, int N) {
    __shared__ int sh[256];
    int i = blockIdx.x * 256 + threadIdx.x;
    sh[threadIdx.x] = (i < N) ? cnt[i] : 0;
    __syncthreads();
    for (int s = 128; s > 0; s >>= 1) {
        if (threadIdx.x < s) sh[threadIdx.x] += sh[threadIdx.x + s];
        __syncthreads();
    }
    if (threadIdx.x == 0) blk[blockIdx.x] = sh[0];
}

__global__ void k_blkscan(int* __restrict__ blk, int nb) {
    __shared__ int sh[1024];
    int t = threadIdx.x;
    sh[t] = (t < nb) ? blk[t] : 0;
    __syncthreads();
    for (int off = 1; off < 1024; off <<= 1) {
        int v = (t >= off) ? sh[t - off] : 0;
        __syncthreads();
        sh[t] += v;
        __syncthreads();
    }
    if (t < nb) blk[t] = (t > 0) ? sh[t - 1] : 0;  // exclusive
}

__global__ void k_rowoff(const int* __restrict__ cnt, const int* __restrict__ blk,
                         int* __restrict__ roff, int* __restrict__ rend, int N) {
    __shared__ int sh[256];
    int t = threadIdx.x;
    int i = blockIdx.x * 256 + t;
    int v = (i < N) ? cnt[i] : 0;
    sh[t] = v;
    __syncthreads();
    for (int off = 1; off < 256; off <<= 1) {
        int u = (t >= off) ? sh[t - off] : 0;
        __syncthreads();
        sh[t] += u;
        __syncthreads();
    }
    if (i < N) {
        int o = blk[blockIdx.x] + sh[t] - v;   // exclusive prefix
        roff[i] = o;
        rend[i] = o + v;
    }
}

// edge-parallel fill: all reads coalesced; scattered 4B writes into L2-resident CSR.
__global__ void k_fillE(const int* __restrict__ src, const int* __restrict__ dst,
                        const float* __restrict__ w, const int* __restrict__ rank,
                        const int* __restrict__ roff, int* __restrict__ csrc,
                        float* __restrict__ cw, int E) {
    int e = blockIdx.x * blockDim.x + threadIdx.x;
    if (e < E) {
        int pos = roff[dst[e]] + rank[e];
        csrc[pos] = src[e];
        cw[pos]   = w[e];
    }
}

// weighted degree from CSR order (coalesced-ish), dis = rsqrt(deg) or 0
__global__ void k_deg_dis(const int* __restrict__ roff, const int* __restrict__ rend,
                          const float* __restrict__ cw, float* __restrict__ dis, int N) {
    int i = blockIdx.x * blockDim.x + threadIdx.x;
    if (i >= N) return;
    float dg = 0.f;
    for (int j = roff[i]; j < rend[i]; ++j) dg += cw[j];
    dis[i] = (dg > 0.f) ? rsqrtf(dg) : 0.f;
}

// cval[j] = dis[dst] * w * dis[src], in place over cw
__global__ void k_val(const int* __restrict__ roff, const int* __restrict__ rend,
                      const int* __restrict__ csrc, const float* __restrict__ dis,
                      float* __restrict__ cval, int N) {
    int i = blockIdx.x * blockDim.x + threadIdx.x;
    if (i >= N) return;
    float di = dis[i];
    for (int j = roff[i]; j < rend[i]; ++j)
        cval[j] = di * cval[j] * dis[csrc[j]];
}

// fp32 -> bf16 row conversion (thread = 8 dims)
__global__ void k_cvt(const float4* __restrict__ x, uint4* __restrict__ xb, int n8) {
    int i = blockIdx.x * blockDim.x + threadIdx.x;
    if (i >= n8) return;
    float4 a = x[2 * i], b = x[2 * i + 1];
    float t[8] = {a.x, a.y, a.z, a.w, b.x, b.y, b.z, b.w};
    xb[i] = pack8(t);
}

// ---------- pull SpMM: 8-lane group per row (8 rows/wave), bf16 gathers ----------
__global__ void k_spmm8(const int* __restrict__ roff, const int* __restrict__ rend,
                        const int* __restrict__ csrc, const float* __restrict__ cval,
                        const uint4* __restrict__ xb, uint4* __restrict__ xn, int N) {
    int idx = blockIdx.x * blockDim.x + threadIdx.x;
    int row = idx >> 3;
    if (row >= N) return;
    int g = idx & 7;
    int s = roff[row], e = rend[row];
    float acc[8] = {0.f, 0.f, 0.f, 0.f, 0.f, 0.f, 0.f, 0.f};
    int j = s;
    for (; j + 1 < e; j += 2) {           // unroll-2: 16 gathers in flight per wave
        int   s0 = csrc[j],   s1 = csrc[j + 1];
        float v0 = cval[j],   v1 = cval[j + 1];
        uint4 a0 = xb[s0 * 8 + g];
        uint4 a1 = xb[s1 * 8 + g];
        bf8_fma(acc, a0, v0);
        bf8_fma(acc, a1, v1);
    }
    if (j < e) {
        uint4 a0 = xb[csrc[j] * 8 + g];
        bf8_fma(acc, a0, cval[j]);
    }
    xn[row * 8 + g] = pack8(acc);
}

// final layer, fused epilogue: out = alpha*(x0 + x1 + x2 + A*x2)
__global__ void k_spmm8_final(const int* __restrict__ roff, const int* __restrict__ rend,
                              const int* __restrict__ csrc, const float* __restrict__ cval,
                              const uint4* __restrict__ x2b, const uint4* __restrict__ x1b,
                              const float4* __restrict__ x0, float4* __restrict__ out,
                              float alpha, int N) {
    int idx = blockIdx.x * blockDim.x + threadIdx.x;
    int row = idx >> 3;
    if (row >= N) return;
    int g = idx & 7;
    int s = roff[row], e = rend[row];
    float acc[8] = {0.f, 0.f, 0.f, 0.f, 0.f, 0.f, 0.f, 0.f};
    int j = s;
    for (; j + 1 < e; j += 2) {
        int   s0 = csrc[j],   s1 = csrc[j + 1];
        float v0 = cval[j],   v1 = cval[j + 1];
        uint4 a0 = x2b[s0 * 8 + g];
        uint4 a1 = x2b[s1 * 8 + g];
        bf8_fma(acc, a0, v0);
        bf8_fma(acc, a1, v1);
    }
    if (j < e) {
        uint4 a0 = x2b[csrc[j] * 8 + g];
        bf8_fma(acc, a0, cval[j]);
    }
    bf8_add(acc, x1b[row * 8 + g]);       // + x1
    bf8_add(acc, x2b[row * 8 + g]);       // + x2
    float4 b0 = x0[row * 16 + 2 * g];
    float4 b1 = x0[row * 16 + 2 * g + 1];
    out[row * 16 + 2 * g] = make_float4(alpha * (b0.x + acc[0]), alpha * (b0.y + acc[1]),
                                        alpha * (b0.z + acc[2]), alpha * (b0.w + acc[3]));
    out[row * 16 + 2 * g + 1] = make_float4(alpha * (b1.x + acc[4]), alpha * (b1.y + acc[5]),
                                            alpha * (b1.z + acc[6]), alpha * (b1.w + acc[7]));
}

// ---------- host-side orchestration ----------

static void run_graph(const int* src, const int* dst, const float* w, int E, int N,
                      const float* x0, float* out,
                      uint4* xb0, uint4* x1, uint4* x2,
                      int* csrc, float* cval, int* rank, int* cnt,
                      int* roff, int* rend, float* dis, int* blk,
                      hipStream_t stream) {
    const int B = 256;
    const int nbE = (E + B - 1) / B;
    const int nbN = (N + B - 1) / B;
    const float alpha = 0.25f;   // 1/(L+1), L=3

    hipMemsetAsync(cnt, 0, (size_t)N * sizeof(int), stream);
    k_cnt_rank<<<nbE, B, 0, stream>>>(dst, cnt, rank, E);
    k_blkred  <<<nbN, B, 0, stream>>>(cnt, blk, N);
    k_blkscan <<<1, 1024, 0, stream>>>(blk, nbN);
    k_rowoff  <<<nbN, B, 0, stream>>>(cnt, blk, roff, rend, N);
    k_fillE   <<<nbE, B, 0, stream>>>(src, dst, w, rank, roff, csrc, cval, E);
    k_deg_dis <<<nbN, B, 0, stream>>>(roff, rend, cval, dis, N);
    k_val     <<<nbN, B, 0, stream>>>(roff, rend, csrc, dis, cval, N);

    const int n8 = N * 8;
    const int ng = (n8 + B - 1) / B;
    k_cvt<<<ng, B, 0, stream>>>((const float4*)x0, xb0, n8);
    // layer 0: xb0 -> x1
    k_spmm8<<<ng, B, 0, stream>>>(roff, rend, csrc, cval, xb0, x1, N);
    // layer 1: x1 -> x2
    k_spmm8<<<ng, B, 0, stream>>>(roff, rend, csrc, cval, x1, x2, N);
    // layer 2 fused: out = alpha*(x0 + x1 + x2 + A*x2)
    k_spmm8_final<<<ng, B, 0, stream>>>(roff, rend, csrc, cval, x2, x1,
                                        (const float4*)x0, (float4*)out, alpha, N);
}

extern "C" void kernel_launch(void* const* d_in, const int* in_sizes, int n_in,
                              void* d_out, int out_size, void* d_ws, size_t ws_size,
                              hipStream_t stream) {
    const float* emb_ii  = (const float*)d_in[0];
    float*       emb_uiu = (float*)d_in[1];        // mutated; harness restores pre-launch
    const float* w_ii    = (const float*)d_in[2];
    const float* w_uiu   = (const float*)d_in[3];
    const int*   src_ii  = (const int*)d_in[4];
    const int*   dst_ii  = src_ii + E_II;
    const int*   src_uiu = (const int*)d_in[5];
    const int*   dst_uiu = src_uiu + E_UIU;
    float*       out     = (float*)d_out;

    // workspace (~94.4 MB, sized for uiu):
    //   xb0 | x1 | x2   : 3 x N_UIU*8 uint4 (bf16 rows)      = 76.8 MB
    //   csrc | cval | rank : E_UIU ints/floats each           = 14.4 MB
    //   cnt | roff | rend | dis : N_UIU each                  =  3.2 MB
    //   blk : 1024 ints
    uint4* xb0  = (uint4*)d_ws;
    uint4* x1   = xb0 + (size_t)N_UIU * 8;
    uint4* x2   = x1 + (size_t)N_UIU * 8;
    int*   csrc = (int*)(x2 + (size_t)N_UIU * 8);
    float* cval = (float*)(csrc + E_UIU);
    int*   rank = (int*)(cval + E_UIU);
    int*   cnt  = rank + E_UIU;
    int*   roff = cnt + N_UIU;
    int*   rend = roff + N_UIU;
    float* dis  = (float*)(rend + N_UIU);
    int*   blk  = (int*)(dis + N_UIU);

    // ---- item-item graph: h_ii written straight into emb_uiu's item block ----
    float* hii = emb_uiu + (size_t)N_USERS * D;
    run_graph(src_ii, dst_ii, w_ii, E_II, N_II, emb_ii, hii,
              xb0, x1, x2, csrc, cval, rank, cnt, roff, rend, dis, blk, stream);

    // ---- user-item graph: x0 = emb_uiu (item block now holds h_ii) ----
    run_graph(src_uiu, dst_uiu, w_uiu, E_UIU, N_UIU, emb_uiu, out,
              xb0, x1, x2, csrc, cval, rank, cnt, roff, rend, dis, blk, stream);
}

// Round 6
// 488.195 us; speedup vs baseline: 3.2242x; 1.0337x over previous
//
#include <hip/hip_runtime.h>

// BigraphLightModel — R5: packed CSR payload (1x8B scattered store/edge),
//   order-free row allocation (single scan kernel, atomic block base),
//   graph1->graph2 bf16 handoff (final epilogue emits bf16 item rows).
//   R4 profile: k_fillE 58us, WRITE=83.7MB — two 4B scattered stores/edge
//   dirtied 2 lines each; int2 packing halves scattered line traffic.

#define D       64
#define N_II    100000
#define N_UIU   200000
#define E_II    600000
#define E_UIU   1200000
#define N_USERS 100000

// ---------- bf16 helpers ----------
__device__ __forceinline__ unsigned short f2bf(float f) {
    unsigned u = __float_as_uint(f);
    u += 0x7fffu + ((u >> 16) & 1u);          // round-to-nearest-even
    return (unsigned short)(u >> 16);
}
__device__ __forceinline__ void bf8_fma(float acc[8], uint4 p, float v) {
    acc[0] += v * __uint_as_float(p.x << 16);
    acc[1] += v * __uint_as_float(p.x & 0xffff0000u);
    acc[2] += v * __uint_as_float(p.y << 16);
    acc[3] += v * __uint_as_float(p.y & 0xffff0000u);
    acc[4] += v * __uint_as_float(p.z << 16);
    acc[5] += v * __uint_as_float(p.z & 0xffff0000u);
    acc[6] += v * __uint_as_float(p.w << 16);
    acc[7] += v * __uint_as_float(p.w & 0xffff0000u);
}
__device__ __forceinline__ void bf8_add(float acc[8], uint4 p) {
    acc[0] += __uint_as_float(p.x << 16);
    acc[1] += __uint_as_float(p.x & 0xffff0000u);
    acc[2] += __uint_as_float(p.y << 16);
    acc[3] += __uint_as_float(p.y & 0xffff0000u);
    acc[4] += __uint_as_float(p.z << 16);
    acc[5] += __uint_as_float(p.z & 0xffff0000u);
    acc[6] += __uint_as_float(p.w << 16);
    acc[7] += __uint_as_float(p.w & 0xffff0000u);
}
__device__ __forceinline__ uint4 pack8(const float a[8]) {
    uint4 r;
    r.x = (unsigned)f2bf(a[0]) | ((unsigned)f2bf(a[1]) << 16);
    r.y = (unsigned)f2bf(a[2]) | ((unsigned)f2bf(a[3]) << 16);
    r.z = (unsigned)f2bf(a[4]) | ((unsigned)f2bf(a[5]) << 16);
    r.w = (unsigned)f2bf(a[6]) | ((unsigned)f2bf(a[7]) << 16);
    return r;
}

// ---------- CSR build ----------

// rank[e] = arrival order within dst bucket; cnt[i] ends as in-degree.
__global__ void k_cnt_rank(const int* __restrict__ dst, int* __restrict__ cnt,
                           int* __restrict__ rank, int E) {
    int e = blockIdx.x * blockDim.x + threadIdx.x;
    if (e < E) rank[e] = atomicAdd(&cnt[dst[e]], 1);
}

// order-free row allocation: block-local scan + atomic base. One dispatch.
__global__ void k_rowoff(const int* __restrict__ cnt, int* __restrict__ roff,
                         int* __restrict__ rend, int* __restrict__ gcur, int N) {
    __shared__ int sh[256];
    __shared__ int base;
    int t = threadIdx.x;
    int i = blockIdx.x * 256 + t;
    int v = (i < N) ? cnt[i] : 0;
    sh[t] = v;
    __syncthreads();
    for (int off = 1; off < 256; off <<= 1) {   // inclusive scan
        int u = (t >= off) ? sh[t - off] : 0;
        __syncthreads();
        sh[t] += u;
        __syncthreads();
    }
    if (t == 255) base = atomicAdd(gcur, sh[255]);
    __syncthreads();
    if (i < N) {
        int o = base + sh[t] - v;
        roff[i] = o;
        rend[i] = o + v;
    }
}

// edge-parallel fill: coalesced reads, ONE scattered 8B store per edge.
__global__ void k_fillE(const int* __restrict__ src, const int* __restrict__ dst,
                        const float* __restrict__ w, const int* __restrict__ rank,
                        const int* __restrict__ roff, int2* __restrict__ ev, int E) {
    int e = blockIdx.x * blockDim.x + threadIdx.x;
    if (e < E) {
        int pos = roff[dst[e]] + rank[e];
        ev[pos] = make_int2(src[e], __float_as_int(w[e]));
    }
}

// weighted degree from CSR order; dis = rsqrt(deg) or 0
__global__ void k_deg_dis(const int* __restrict__ roff, const int* __restrict__ rend,
                          const int2* __restrict__ ev, float* __restrict__ dis, int N) {
    int i = blockIdx.x * blockDim.x + threadIdx.x;
    if (i >= N) return;
    float dg = 0.f;
    for (int j = roff[i]; j < rend[i]; ++j) dg += __int_as_float(ev[j].y);
    dis[i] = (dg > 0.f) ? rsqrtf(dg) : 0.f;
}

// ev[j].y: w -> dis[dst]*w*dis[src], in place
__global__ void k_val(const int* __restrict__ roff, const int* __restrict__ rend,
                      const float* __restrict__ dis, int2* __restrict__ ev, int N) {
    int i = blockIdx.x * blockDim.x + threadIdx.x;
    if (i >= N) return;
    float di = dis[i];
    for (int j = roff[i]; j < rend[i]; ++j) {
        int2 p = ev[j];
        ev[j].y = __float_as_int(di * __int_as_float(p.y) * dis[p.x]);
    }
}

// fp32 -> bf16 row conversion (thread = 8 dims)
__global__ void k_cvt(const float4* __restrict__ x, uint4* __restrict__ xb, int n8) {
    int i = blockIdx.x * blockDim.x + threadIdx.x;
    if (i >= n8) return;
    float4 a = x[2 * i], b = x[2 * i + 1];
    float t[8] = {a.x, a.y, a.z, a.w, b.x, b.y, b.z, b.w};
    xb[i] = pack8(t);
}

// ---------- pull SpMM: 8-lane group per row (8 rows/wave), bf16 gathers ----------
__global__ void k_spmm8(const int* __restrict__ roff, const int* __restrict__ rend,
                        const int2* __restrict__ ev, const uint4* __restrict__ xb,
                        uint4* __restrict__ xn, int N) {
    int idx = blockIdx.x * blockDim.x + threadIdx.x;
    int row = idx >> 3;
    if (row >= N) return;
    int g = idx & 7;
    int s = roff[row], e = rend[row];
    float acc[8] = {0.f, 0.f, 0.f, 0.f, 0.f, 0.f, 0.f, 0.f};
    int j = s;
    for (; j + 1 < e; j += 2) {           // unroll-2: 16 gathers in flight per wave
        int2 p0 = ev[j], p1 = ev[j + 1];
        uint4 a0 = xb[p0.x * 8 + g];
        uint4 a1 = xb[p1.x * 8 + g];
        bf8_fma(acc, a0, __int_as_float(p0.y));
        bf8_fma(acc, a1, __int_as_float(p1.y));
    }
    if (j < e) {
        int2 p0 = ev[j];
        uint4 a0 = xb[p0.x * 8 + g];
        bf8_fma(acc, a0, __int_as_float(p0.y));
    }
    xn[row * 8 + g] = pack8(acc);
}

// final layer, fused epilogue: res = alpha*(x0 + x1 + x2 + A*x2)
// out (fp32) always written; outb (bf16) optionally (graph1 -> graph2 handoff).
__global__ void k_spmm8_final(const int* __restrict__ roff, const int* __restrict__ rend,
                              const int2* __restrict__ ev, const uint4* __restrict__ x2b,
                              const uint4* __restrict__ x1b, const float4* __restrict__ x0,
                              float4* __restrict__ out, uint4* __restrict__ outb,
                              float alpha, int N) {
    int idx = blockIdx.x * blockDim.x + threadIdx.x;
    int row = idx >> 3;
    if (row >= N) return;
    int g = idx & 7;
    int s = roff[row], e = rend[row];
    float acc[8] = {0.f, 0.f, 0.f, 0.f, 0.f, 0.f, 0.f, 0.f};
    int j = s;
    for (; j + 1 < e; j += 2) {
        int2 p0 = ev[j], p1 = ev[j + 1];
        uint4 a0 = x2b[p0.x * 8 + g];
        uint4 a1 = x2b[p1.x * 8 + g];
        bf8_fma(acc, a0, __int_as_float(p0.y));
        bf8_fma(acc, a1, __int_as_float(p1.y));
    }
    if (j < e) {
        int2 p0 = ev[j];
        uint4 a0 = x2b[p0.x * 8 + g];
        bf8_fma(acc, a0, __int_as_float(p0.y));
    }
    bf8_add(acc, x1b[row * 8 + g]);       // + x1
    bf8_add(acc, x2b[row * 8 + g]);       // + x2
    float4 b0 = x0[row * 16 + 2 * g];
    float4 b1 = x0[row * 16 + 2 * g + 1];
    float r[8] = {alpha * (b0.x + acc[0]), alpha * (b0.y + acc[1]),
                  alpha * (b0.z + acc[2]), alpha * (b0.w + acc[3]),
                  alpha * (b1.x + acc[4]), alpha * (b1.y + acc[5]),
                  alpha * (b1.z + acc[6]), alpha * (b1.w + acc[7])};
    out[row * 16 + 2 * g]     = make_float4(r[0], r[1], r[2], r[3]);
    out[row * 16 + 2 * g + 1] = make_float4(r[4], r[5], r[6], r[7]);
    if (outb) outb[row * 8 + g] = pack8(r);
}

// ---------- host-side orchestration ----------

static void build_csr(const int* src, const int* dst, const float* w, int E, int N,
                      int2* ev, int* rank, int* cnt, int* roff, int* rend,
                      float* dis, hipStream_t stream) {
    const int B = 256;
    const int nbE = (E + B - 1) / B;
    const int nbN = (N + B - 1) / B;
    int* gcur = cnt + N;                              // zeroed together with cnt
    hipMemsetAsync(cnt, 0, ((size_t)N + 1) * sizeof(int), stream);
    k_cnt_rank<<<nbE, B, 0, stream>>>(dst, cnt, rank, E);
    k_rowoff  <<<nbN, B, 0, stream>>>(cnt, roff, rend, gcur, N);
    k_fillE   <<<nbE, B, 0, stream>>>(src, dst, w, rank, roff, ev, E);
    k_deg_dis <<<nbN, B, 0, stream>>>(roff, rend, ev, dis, N);
    k_val     <<<nbN, B, 0, stream>>>(roff, rend, dis, ev, N);
}

extern "C" void kernel_launch(void* const* d_in, const int* in_sizes, int n_in,
                              void* d_out, int out_size, void* d_ws, size_t ws_size,
                              hipStream_t stream) {
    const float* emb_ii  = (const float*)d_in[0];
    float*       emb_uiu = (float*)d_in[1];        // mutated; harness restores pre-launch
    const float* w_ii    = (const float*)d_in[2];
    const float* w_uiu   = (const float*)d_in[3];
    const int*   src_ii  = (const int*)d_in[4];
    const int*   dst_ii  = src_ii + E_II;
    const int*   src_uiu = (const int*)d_in[5];
    const int*   dst_uiu = src_uiu + E_UIU;
    float*       out     = (float*)d_out;

    // workspace (~95 MB):
    //   xb0_u | x1_u | x2_u : 3 x N_UIU*8 uint4 (bf16 rows, 25.6MB each)
    //   ev [E_UIU int2] | rank [E_UIU] | cnt [N_UIU+1] | roff | rend | dis [N_UIU]
    // graph1's three 12.8MB bf16 buffers are carved out of x1_u / x2_u.
    uint4* xb0_u = (uint4*)d_ws;
    uint4* x1_u  = xb0_u + (size_t)N_UIU * 8;
    uint4* x2_u  = x1_u + (size_t)N_UIU * 8;
    int2*  ev    = (int2*)(x2_u + (size_t)N_UIU * 8);
    int*   rank  = (int*)(ev + E_UIU);
    int*   cnt   = rank + E_UIU;
    int*   roff  = cnt + N_UIU + 1;
    int*   rend  = roff + N_UIU;
    float* dis   = (float*)(rend + N_UIU);

    uint4* g1_x0 = x1_u;                              // 12.8MB
    uint4* g1_x1 = x1_u + (size_t)N_II * 8;           // 12.8MB
    uint4* g1_x2 = x2_u;                              // 12.8MB

    const int B = 256;
    const float alpha = 0.25f;   // 1/(L+1), L=3 for both graphs

    // ================= item-item graph =================
    build_csr(src_ii, dst_ii, w_ii, E_II, N_II, ev, rank, cnt, roff, rend, dis, stream);
    {
        const int n8 = N_II * 8;
        const int ng = (n8 + B - 1) / B;
        float* hii = emb_uiu + (size_t)N_USERS * D;   // fp32 result -> emb_uiu item block
        uint4* hii_b = xb0_u + (size_t)N_USERS * 8;   // bf16 result -> graph2 x0 item block
        k_cvt  <<<ng, B, 0, stream>>>((const float4*)emb_ii, g1_x0, n8);
        k_spmm8<<<ng, B, 0, stream>>>(roff, rend, ev, g1_x0, g1_x1, N_II);
        k_spmm8<<<ng, B, 0, stream>>>(roff, rend, ev, g1_x1, g1_x2, N_II);
        k_spmm8_final<<<ng, B, 0, stream>>>(roff, rend, ev, g1_x2, g1_x1,
                                            (const float4*)emb_ii, (float4*)hii, hii_b,
                                            alpha, N_II);
    }

    // ================= user-item graph =================
    build_csr(src_uiu, dst_uiu, w_uiu, E_UIU, N_UIU, ev, rank, cnt, roff, rend, dis, stream);
    {
        // convert only the user half of x0; item half written bf16 by graph1 final
        const int n8u = N_USERS * 8;
        k_cvt<<<(n8u + B - 1) / B, B, 0, stream>>>((const float4*)emb_uiu, xb0_u, n8u);
        const int n8 = N_UIU * 8;
        const int ng = (n8 + B - 1) / B;
        k_spmm8<<<ng, B, 0, stream>>>(roff, rend, ev, xb0_u, x1_u, N_UIU);
        k_spmm8<<<ng, B, 0, stream>>>(roff, rend, ev, x1_u, x2_u, N_UIU);
        k_spmm8_final<<<ng, B, 0, stream>>>(roff, rend, ev, x2_u, x1_u,
                                            (const float4*)emb_uiu, (float4*)out, nullptr,
                                            alpha, N_UIU);
    }
}